// Round 5
// baseline (1048.694 us; speedup 1.0000x reference)
//
#include <hip/hip_runtime.h>
#include <math.h>

#define NTOT   64000
#define NNODE  1000
#define NBATCH 64
#define NSEQ   12
#define NE     1024000
#define NBLK_L 512

__device__ __forceinline__ float lrelu(float x){ return x > 0.f ? x : 0.2f*x; }
__device__ __forceinline__ float sigmoidf_(float x){ return 1.f/(1.f+__expf(-x)); }

// ---------------- GAT: h = x @ W_gat, per-node attention scalars ----------------
__global__ void __launch_bounds__(256) k_gat_h(const float* __restrict__ x, const float* __restrict__ Wg,
                       const float* __restrict__ att_s, const float* __restrict__ att_d,
                       float* __restrict__ hfeat, float* __restrict__ asrc, float* __restrict__ adst){
  __shared__ __align__(16) float Ws[48*96];
  __shared__ float as_s[96], ad_s[96];
  for (int i = threadIdx.x; i < 48*96; i += 256) Ws[i] = Wg[i];
  if (threadIdx.x < 96){ as_s[threadIdx.x] = att_s[threadIdx.x]; ad_s[threadIdx.x] = att_d[threadIdx.x]; }
  __syncthreads();
  int n = blockIdx.x * 256 + threadIdx.x;
  if (n >= NTOT) return;
  float xr[48];
  const float4* xv = (const float4*)(x + (size_t)n*48);
  #pragma unroll
  for (int q = 0; q < 12; ++q){ float4 v = xv[q]; xr[q*4]=v.x; xr[q*4+1]=v.y; xr[q*4+2]=v.z; xr[q*4+3]=v.w; }
  float a0=0.f,a1=0.f,d0=0.f,d1=0.f;
  float* hrow = hfeat + (size_t)n*96;
  for (int j = 0; j < 96; ++j){
    float acc = 0.f;
    #pragma unroll
    for (int k = 0; k < 48; ++k) acc += xr[k]*Ws[k*96+j];
    hrow[j] = acc;
    if (j < 48){ a0 += acc*as_s[j]; d0 += acc*ad_s[j]; }
    else       { a1 += acc*as_s[j]; d1 += acc*ad_s[j]; }
  }
  asrc[n*2]=a0; asrc[n*2+1]=a1; adst[n*2]=d0; adst[n*2+1]=d1;
}

// ---------------- CSR build ----------------
__global__ void k_count(const int* __restrict__ ei, int* __restrict__ cnt){
  int e = blockIdx.x*256 + threadIdx.x;
  if (e < NE) atomicAdd(&cnt[ei[NE + e]], 1);
}

__global__ void __launch_bounds__(256) k_scan1(const int* __restrict__ cnt, int* __restrict__ wsum){
  int w = (blockIdx.x*256 + threadIdx.x) >> 6;
  int lane = threadIdx.x & 63;
  int v = cnt[w*64 + lane];
  int t = v;
  #pragma unroll
  for (int d = 1; d < 64; d <<= 1) t += __shfl_xor(t, d);
  if (lane == 0) wsum[w] = t;
}

__global__ void __launch_bounds__(1024) k_scan2(int* __restrict__ wsum){
  __shared__ int tmp[1024];
  int k = threadIdx.x;
  int v = (k < 1000) ? wsum[k] : 0;
  tmp[k] = v; __syncthreads();
  for (int d = 1; d < 1024; d <<= 1){
    int t = (k >= d) ? tmp[k-d] : 0;
    __syncthreads();
    tmp[k] += t;
    __syncthreads();
  }
  if (k < 1000) wsum[k] = tmp[k] - v;
}

__global__ void __launch_bounds__(256) k_scan3(const int* __restrict__ cnt, const int* __restrict__ wpre,
                                               int* __restrict__ offs, int* __restrict__ cursor){
  int w = (blockIdx.x*256 + threadIdx.x) >> 6;
  int lane = threadIdx.x & 63;
  int i = w*64 + lane;
  int v = cnt[i];
  int x = v;
  #pragma unroll
  for (int d = 1; d < 64; d <<= 1){
    int t = __shfl_up(x, d);
    if (lane >= d) x += t;
  }
  int excl = wpre[w] + x - v;
  offs[i] = excl; cursor[i] = excl;
  if (i == NTOT-1) offs[NTOT] = excl + v;
}

__global__ void k_scatter(const int* __restrict__ ei, int* __restrict__ cursor, int* __restrict__ csr){
  int e = blockIdx.x*256 + threadIdx.x;
  if (e < NE){
    int d = ei[NE + e], s = ei[e];
    int pos = atomicAdd(&cursor[d], 1);
    csr[pos] = s;
  }
}

// ---------------- per-node softmax + aggregation + scatter into x_seq ----------------
__global__ void __launch_bounds__(256) k_node(const float* __restrict__ hfeat, const float* __restrict__ asrc,
                      const float* __restrict__ adst, const int* __restrict__ offs,
                      const int* __restrict__ csr, const float* __restrict__ bias,
                      float* __restrict__ xseq){
  __shared__ float gsh[4][96];
  int wv = threadIdx.x >> 6, lane = threadIdx.x & 63;
  int n = blockIdx.x*4 + wv;
  int off = offs[n], deg = offs[n+1] - off;
  const float2* as2 = (const float2*)asrc;
  float2 adn = ((const float2*)adst)[n];
  float2 asn = as2[n];
  float es0 = __expf(lrelu(asn.x + adn.x));
  float es1 = __expf(lrelu(asn.y + adn.y));
  float s0 = 0.f, s1 = 0.f;
  for (int i = lane; i < deg; i += 64){
    int s = csr[off+i];
    float2 a = as2[s];
    s0 += __expf(lrelu(a.x + adn.x));
    s1 += __expf(lrelu(a.y + adn.y));
  }
  #pragma unroll
  for (int d = 1; d < 64; d <<= 1){
    s0 += __shfl_xor(s0, d);
    s1 += __shfl_xor(s1, d);
  }
  s0 += es0; s1 += es1;
  float inv0 = 1.f/(s0 + 1e-16f), inv1 = 1.f/(s1 + 1e-16f);
  int cl = (lane < 48) ? lane : lane - 48;
  float2 acc = make_float2(0.f, 0.f);
  {
    const float2* hr = (const float2*)(hfeat + (size_t)n*96);
    float2 r = hr[cl];
    float al = (lane < 24) ? es0*inv0 : es1*inv1;
    acc.x += r.x*al; acc.y += r.y*al;
  }
  int i = 0;
  for (; i + 4 <= deg; i += 4){
    int ss[4];
    #pragma unroll
    for (int j = 0; j < 4; ++j) ss[j] = csr[off+i+j];
    float2 aa[4];
    #pragma unroll
    for (int j = 0; j < 4; ++j) aa[j] = as2[ss[j]];
    #pragma unroll
    for (int j = 0; j < 4; ++j){
      const float2* hr = (const float2*)(hfeat + (size_t)ss[j]*96);
      float2 r = hr[cl];
      float w0 = __expf(lrelu(aa[j].x + adn.x));
      float w1 = __expf(lrelu(aa[j].y + adn.y));
      float al = (lane < 24) ? w0*inv0 : w1*inv1;
      acc.x += r.x*al; acc.y += r.y*al;
    }
  }
  for (; i < deg; ++i){
    int s = csr[off+i];
    float2 a = as2[s];
    const float2* hr = (const float2*)(hfeat + (size_t)s*96);
    float2 r = hr[cl];
    float w0 = __expf(lrelu(a.x + adn.x));
    float w1 = __expf(lrelu(a.y + adn.y));
    float al = (lane < 24) ? w0*inv0 : w1*inv1;
    acc.x += r.x*al; acc.y += r.y*al;
  }
  if (lane < 48){ gsh[wv][2*lane] = acc.x; gsh[wv][2*lane+1] = acc.y; }
  __syncthreads();
  if (lane < 48){
    float g = 0.5f*(gsh[wv][lane] + gsh[wv][48+lane]) + bias[lane];
    int b = n / 1000, node = n - b*1000;
    int t = lane >> 2, f = lane & 3;
    xseq[((size_t)(t*64 + b))*4000 + node*4 + f] = g;
  }
}

// ---------------- GEMM1: xw1_part = x_seq[768x4000] @ W_ih1^T[4000x1024], split-K=5 ----------------
__global__ void __launch_bounds__(256) k_gemm1(const float* __restrict__ A, const float* __restrict__ B,
                       float* __restrict__ part){
  __shared__ __align__(16) float As[32*72];
  __shared__ __align__(16) float Bs[32*72];
  int tid = threadIdx.x;
  int tx = tid & 15, ty = tid >> 4;
  int m0 = blockIdx.x*64, n0 = blockIdx.y*64;
  int k0 = blockIdx.z*800;
  float acc[4][4] = {};
  for (int kk = 0; kk < 800; kk += 32){
    #pragma unroll
    for (int l = 0; l < 2; ++l){
      int q = tid + l*256;
      int r = q >> 3, c4 = (q & 7)*4;
      float4 va = *(const float4*)(A + (size_t)(m0+r)*4000 + k0+kk+c4);
      As[(c4+0)*72 + r] = va.x; As[(c4+1)*72 + r] = va.y;
      As[(c4+2)*72 + r] = va.z; As[(c4+3)*72 + r] = va.w;
      float4 vb = *(const float4*)(B + (size_t)(n0+r)*4000 + k0+kk+c4);
      Bs[(c4+0)*72 + r] = vb.x; Bs[(c4+1)*72 + r] = vb.y;
      Bs[(c4+2)*72 + r] = vb.z; Bs[(c4+3)*72 + r] = vb.w;
    }
    __syncthreads();
    #pragma unroll
    for (int k = 0; k < 32; ++k){
      float4 a = *(const float4*)(&As[k*72 + ty*4]);
      float4 b = *(const float4*)(&Bs[k*72 + tx*4]);
      acc[0][0] += a.x*b.x; acc[0][1] += a.x*b.y; acc[0][2] += a.x*b.z; acc[0][3] += a.x*b.w;
      acc[1][0] += a.y*b.x; acc[1][1] += a.y*b.y; acc[1][2] += a.y*b.z; acc[1][3] += a.y*b.w;
      acc[2][0] += a.z*b.x; acc[2][1] += a.z*b.y; acc[2][2] += a.z*b.z; acc[2][3] += a.z*b.w;
      acc[3][0] += a.w*b.x; acc[3][1] += a.w*b.y; acc[3][2] += a.w*b.z; acc[3][3] += a.w*b.w;
    }
    __syncthreads();
  }
  #pragma unroll
  for (int i = 0; i < 4; ++i){
    float4 v; v.x = acc[i][0]; v.y = acc[i][1]; v.z = acc[i][2]; v.w = acc[i][3];
    *(float4*)(part + ((size_t)blockIdx.z*768 + m0 + ty*4 + i)*1024 + n0 + tx*4) = v;
  }
}

__global__ void k_reduce1(const float* __restrict__ part, const float* __restrict__ b1,
                          float* __restrict__ xw1){
  int i = blockIdx.x*256 + threadIdx.x;
  int j = i & 1023;
  float v = b1[j];
  #pragma unroll
  for (int s = 0; s < 5; ++s) v += part[(size_t)s*786432 + i];
  xw1[i] = v;
}

// ---------------- weight transposes (K-major for coalesced k_lstm dots) ----------------
__global__ void __launch_bounds__(256) k_tr(const float* __restrict__ Whh1, const float* __restrict__ Wih2,
                    const float* __restrict__ Whh2, const float* __restrict__ Wout,
                    float* __restrict__ dst){
  int i = blockIdx.x*256 + threadIdx.x;
  if (i < 262144){ int q = i>>10, r = i&1023; dst[i] = Whh1[r*256+q]; return; }
  i -= 262144;
  if (i < 131072){ int q = i>>9, r = i&511; dst[262144+i] = Wih2[r*256+q]; return; }
  i -= 131072;
  if (i < 65536){ int q = i>>9, r = i&511; dst[393216+i] = Whh2[(size_t)r*128+q]; return; }
  i -= 65536;
  if (i < 256000){ int q = i/2000, r = i - q*2000; dst[458752+i] = Wout[(size_t)r*128+q]; }
}

// ---------------- device-wide barrier: monotonic count, READ-polling ----------------
// Round-4 lesson: spinning with atomicAdd(p,0) is a device-scope RMW -> 511 blocks
// ping-pong exclusive ownership of one line across 8 XCDs (~45us/barrier).
// Arrival: one relaxed fetch_add. Spin: relaxed device-scope LOAD (read-shared,
// no ownership). Cumulative target -> no counter reset, no reset race.
__device__ __forceinline__ void gbar(int* cnt, int target){
  __syncthreads();
  if (threadIdx.x == 0){
    __threadfence();   // release: flush h1g/h2g stores to device scope
    __hip_atomic_fetch_add(cnt, 1, __ATOMIC_RELAXED, __HIP_MEMORY_SCOPE_AGENT);
    while (__hip_atomic_load(cnt, __ATOMIC_RELAXED, __HIP_MEMORY_SCOPE_AGENT) < target)
      __builtin_amdgcn_s_sleep(8);
    __threadfence();   // acquire: invalidate stale lines before reading peers' h
  }
  __syncthreads();
}

// ---------------- fused 2-layer LSTM + output projection, persistent grid ----------------
__global__ void __launch_bounds__(256, 2) k_lstm(
    const float* __restrict__ xw1, const float* __restrict__ Wt1,
    const float* __restrict__ Wt2i, const float* __restrict__ Wt2h,
    const float* __restrict__ b2, const float* __restrict__ Wt_o,
    const float* __restrict__ bout,
    float* __restrict__ h1g, float* __restrict__ h2g,
    int* __restrict__ bar, float* __restrict__ out){
  __shared__ float h1s[2][256];
  __shared__ float h2s[2][128];
  __shared__ __align__(16) float pA[256][4];
  __shared__ __align__(16) float pB[256][4];
  int t = threadIdx.x;
  int bg = blockIdx.x >> 4, s = blockIdx.x & 15;
  int b0 = bg*2;
  int bt = 0;
  if (t < 32) h1g[(size_t)(b0 + (t>>4))*256 + s*16 + (t&15)] = 0.f;
  if (t < 16) h2g[(size_t)(b0 + (t>>3))*128 + s*8 + (t&7)] = 0.f;
  float c1r = 0.f;
  float c2r = 0.f;
  gbar(bar, (++bt)*NBLK_L);

  int kcA = t >> 5, pApx = t & 31;
  int r0A = (pApx >> 3)*256 + s*16 + 2*(pApx & 7);
  int kcB = t >> 4, pBpx = t & 15;
  int r0B = (pBpx >> 2)*128 + s*8 + 2*(pBpx & 3);

  float* h1f = &h1s[0][0];
  float* h2f = &h2s[0][0];

  for (int k = 0; k <= 12; ++k){
    {
      const float* h1src = h1g + (size_t)(k&1)*16384 + (size_t)b0*256;
      const float* h2src = h2g + (size_t)((k+1)&1)*8192 + (size_t)b0*128;
      h1f[t] = h1src[t];
      h1f[t+256] = h1src[t+256];
      h2f[t] = h2src[t];
    }
    __syncthreads();
    if (k < 12){
      float a0x=0.f, a0y=0.f, a1x=0.f, a1y=0.f;
      const float* wp = Wt1 + (size_t)(kcA*32)*1024 + r0A;
      const float* hb = &h1s[0][kcA*32];
      #pragma unroll 8
      for (int q = 0; q < 32; ++q){
        float2 w = *(const float2*)(wp + (size_t)q*1024);
        float hq0 = hb[q], hq1 = hb[256+q];
        a0x += w.x*hq0; a0y += w.y*hq0;
        a1x += w.x*hq1; a1y += w.y*hq1;
      }
      float4 v; v.x=a0x; v.y=a0y; v.z=a1x; v.w=a1y;
      *(float4*)pA[t] = v;
    }
    if (k >= 1){
      float q0x=0.f, q0y=0.f, q1x=0.f, q1y=0.f;
      const float* wi = Wt2i + (size_t)(kcB*16)*512 + r0B;
      const float* hb1 = &h1s[0][kcB*16];
      #pragma unroll 8
      for (int q = 0; q < 16; ++q){
        float2 w = *(const float2*)(wi + (size_t)q*512);
        float hq0 = hb1[q], hq1 = hb1[256+q];
        q0x += w.x*hq0; q0y += w.y*hq0;
        q1x += w.x*hq1; q1y += w.y*hq1;
      }
      const float* wh = Wt2h + (size_t)(kcB*8)*512 + r0B;
      const float* hb2 = &h2s[0][kcB*8];
      #pragma unroll 8
      for (int q = 0; q < 8; ++q){
        float2 w = *(const float2*)(wh + (size_t)q*512);
        float hq0 = hb2[q], hq1 = hb2[128+q];
        q0x += w.x*hq0; q0y += w.y*hq0;
        q1x += w.x*hq1; q1y += w.y*hq1;
      }
      float4 v; v.x=q0x; v.y=q0y; v.z=q1x; v.w=q1y;
      *(float4*)pB[t] = v;
    }
    __syncthreads();
    if (k < 12 && t < 32){
      int bb = t >> 4, j = t & 15;
      int u = s*16 + j;
      float xg[4];
      #pragma unroll
      for (int gi = 0; gi < 4; ++gi)
        xg[gi] = xw1[((size_t)k*64 + b0+bb)*1024 + gi*256 + u];
      float g[4];
      #pragma unroll
      for (int gi = 0; gi < 4; ++gi){
        int p = gi*8 + (j>>1);
        int e = bb*2 + (j&1);
        float sum = 0.f;
        #pragma unroll
        for (int kc = 0; kc < 8; ++kc) sum += pA[kc*32 + p][e];
        g[gi] = xg[gi] + sum;
      }
      float i_ = sigmoidf_(g[0]);
      float f_ = sigmoidf_(g[1]);
      float gg = tanhf(g[2]);
      float o_ = sigmoidf_(g[3]);
      c1r = f_*c1r + i_*gg;
      float h = o_*tanhf(c1r);
      h1g[(size_t)((k+1)&1)*16384 + (size_t)(b0+bb)*256 + u] = h;
    }
    if (k >= 1 && t >= 32 && t < 48){
      int tt = t - 32;
      int bb = tt >> 3, j = tt & 7;
      int u = s*8 + j;
      float bg4[4];
      #pragma unroll
      for (int gi = 0; gi < 4; ++gi) bg4[gi] = b2[gi*128 + u];
      float g[4];
      #pragma unroll
      for (int gi = 0; gi < 4; ++gi){
        int p = gi*4 + (j>>1);
        int e = bb*2 + (j&1);
        float sum = 0.f;
        #pragma unroll
        for (int kc = 0; kc < 16; ++kc) sum += pB[kc*16 + p][e];
        g[gi] = bg4[gi] + sum;
      }
      float i_ = sigmoidf_(g[0]);
      float f_ = sigmoidf_(g[1]);
      float gg = tanhf(g[2]);
      float o_ = sigmoidf_(g[3]);
      c2r = f_*c2r + i_*gg;
      float h = o_*tanhf(c2r);
      h2g[(size_t)(k&1)*8192 + (size_t)(b0+bb)*128 + u] = h;
    }
    gbar(bar, (++bt)*NBLK_L);
  }

  {
    const float* h2src = h2g + (size_t)b0*128;
    h2f[t] = h2src[t];
  }
  __syncthreads();
  {
    int bb = t >> 7, i = t & 127;
    if (i < 125){
      int j = s*125 + i;
      float acc = bout[j];
      const float* hb = &h2s[bb][0];
      #pragma unroll 8
      for (int q = 0; q < 128; ++q) acc += hb[q]*Wt_o[(size_t)q*2000 + j];
      out[(size_t)(b0+bb)*2000 + j] = acc;
    }
  }
}

extern "C" void kernel_launch(void* const* d_in, const int* in_sizes, int n_in,
                              void* d_out, int out_size, void* d_ws, size_t ws_size,
                              hipStream_t stream){
  const float* x     = (const float*)d_in[0];
  const int*   ei    = (const int*)d_in[1];
  const float* Wg    = (const float*)d_in[2];
  const float* att_s = (const float*)d_in[3];
  const float* att_d = (const float*)d_in[4];
  const float* gb    = (const float*)d_in[5];
  const float* Wih1  = (const float*)d_in[6];
  const float* Whh1  = (const float*)d_in[7];
  const float* b1    = (const float*)d_in[8];
  const float* Wih2  = (const float*)d_in[9];
  const float* Whh2  = (const float*)d_in[10];
  const float* b2    = (const float*)d_in[11];
  const float* Wout  = (const float*)d_in[12];
  const float* bout  = (const float*)d_in[13];
  float* out = (float*)d_out;

  char* w = (char*)d_ws;
  float* xseq  = (float*)(w);                         // 12,288,000 B
  char*  hbase = w + 12288000;                        // hfeat region: 24,576,000 B
  float* hfeat = (float*)hbase;
  float* part  = (float*)(hbase);                     // 15,728,640 B (gemm1 out)
  float* xw1   = (float*)(hbase + 15728640);          //  3,145,728 B
  float* Wt1   = part;                                // 262144 f
  float* Wt2i  = part + 262144;                       // 131072 f
  float* Wt2h  = part + 393216;                       //  65536 f
  float* Wt_o  = part + 458752;                       // 256000 f
  float* h1g   = part + 714752;                       //  32768 f
  float* h2g   = part + 747520;                       //  16384 f
  char*  p2 = w + 12288000 + 24576000;
  float* asrc   = (float*)(p2);
  float* adst   = (float*)(p2 + 512000);
  int*   cnt    = (int*)(p2 + 1024000);
  int*   offs   = (int*)(p2 + 1280000);
  int*   cursor = (int*)(p2 + 1536256);
  int*   csr    = (int*)(p2 + 1792256);
  int*   bar    = (int*)(p2 + 5888256);
  int*   wsum   = csr;

  hipMemsetAsync(cnt, 0, NTOT*sizeof(int), stream);
  hipMemsetAsync(bar, 0, 8, stream);

  k_gat_h<<<250, 256, 0, stream>>>(x, Wg, att_s, att_d, hfeat, asrc, adst);
  k_count<<<4000, 256, 0, stream>>>(ei, cnt);
  k_scan1<<<250, 256, 0, stream>>>(cnt, wsum);
  k_scan2<<<1, 1024, 0, stream>>>(wsum);
  k_scan3<<<250, 256, 0, stream>>>(cnt, wsum, offs, cursor);
  k_scatter<<<4000, 256, 0, stream>>>(ei, cursor, csr);
  k_node<<<16000, 256, 0, stream>>>(hfeat, asrc, adst, offs, csr, gb, xseq);

  k_gemm1<<<dim3(12,16,5), 256, 0, stream>>>(xseq, Wih1, part);
  k_reduce1<<<3072, 256, 0, stream>>>(part, b1, xw1);
  k_tr<<<2792, 256, 0, stream>>>(Whh1, Wih2, Whh2, Wout, Wt1);

  k_lstm<<<NBLK_L, 256, 0, stream>>>(xw1, Wt1, Wt2i, Wt2h, b2, Wt_o, bout,
                                     h1g, h2g, bar, out);
}

// Round 6
// 703.493 us; speedup vs baseline: 1.4907x; 1.4907x over previous
//
#include <hip/hip_runtime.h>
#include <math.h>

#define NTOT   64000
#define NNODE  1000
#define NBATCH 64
#define NSEQ   12
#define NE     1024000

__device__ __forceinline__ float lrelu(float x){ return x > 0.f ? x : 0.2f*x; }
__device__ __forceinline__ float sigmoidf_(float x){ return 1.f/(1.f+__expf(-x)); }

// ---------------- GAT: h = x @ W_gat, per-node attention scalars ----------------
__global__ void __launch_bounds__(256) k_gat_h(const float* __restrict__ x, const float* __restrict__ Wg,
                       const float* __restrict__ att_s, const float* __restrict__ att_d,
                       float* __restrict__ hfeat, float* __restrict__ asrc, float* __restrict__ adst){
  __shared__ __align__(16) float Ws[48*96];
  __shared__ float as_s[96], ad_s[96];
  for (int i = threadIdx.x; i < 48*96; i += 256) Ws[i] = Wg[i];
  if (threadIdx.x < 96){ as_s[threadIdx.x] = att_s[threadIdx.x]; ad_s[threadIdx.x] = att_d[threadIdx.x]; }
  __syncthreads();
  int n = blockIdx.x * 256 + threadIdx.x;
  if (n >= NTOT) return;
  float xr[48];
  const float4* xv = (const float4*)(x + (size_t)n*48);
  #pragma unroll
  for (int q = 0; q < 12; ++q){ float4 v = xv[q]; xr[q*4]=v.x; xr[q*4+1]=v.y; xr[q*4+2]=v.z; xr[q*4+3]=v.w; }
  float a0=0.f,a1=0.f,d0=0.f,d1=0.f;
  float* hrow = hfeat + (size_t)n*96;
  for (int j = 0; j < 96; ++j){
    float acc = 0.f;
    #pragma unroll
    for (int k = 0; k < 48; ++k) acc += xr[k]*Ws[k*96+j];
    hrow[j] = acc;
    if (j < 48){ a0 += acc*as_s[j]; d0 += acc*ad_s[j]; }
    else       { a1 += acc*as_s[j]; d1 += acc*ad_s[j]; }
  }
  asrc[n*2]=a0; asrc[n*2+1]=a1; adst[n*2]=d0; adst[n*2+1]=d1;
}

// ---------------- CSR build ----------------
__global__ void k_count(const int* __restrict__ ei, int* __restrict__ cnt){
  int e = blockIdx.x*256 + threadIdx.x;
  if (e < NE) atomicAdd(&cnt[ei[NE + e]], 1);
}

__global__ void __launch_bounds__(256) k_scan1(const int* __restrict__ cnt, int* __restrict__ wsum){
  int w = (blockIdx.x*256 + threadIdx.x) >> 6;
  int lane = threadIdx.x & 63;
  int v = cnt[w*64 + lane];
  int t = v;
  #pragma unroll
  for (int d = 1; d < 64; d <<= 1) t += __shfl_xor(t, d);
  if (lane == 0) wsum[w] = t;
}

__global__ void __launch_bounds__(1024) k_scan2(int* __restrict__ wsum){
  __shared__ int tmp[1024];
  int k = threadIdx.x;
  int v = (k < 1000) ? wsum[k] : 0;
  tmp[k] = v; __syncthreads();
  for (int d = 1; d < 1024; d <<= 1){
    int t = (k >= d) ? tmp[k-d] : 0;
    __syncthreads();
    tmp[k] += t;
    __syncthreads();
  }
  if (k < 1000) wsum[k] = tmp[k] - v;
}

__global__ void __launch_bounds__(256) k_scan3(const int* __restrict__ cnt, const int* __restrict__ wpre,
                                               int* __restrict__ offs, int* __restrict__ cursor){
  int w = (blockIdx.x*256 + threadIdx.x) >> 6;
  int lane = threadIdx.x & 63;
  int i = w*64 + lane;
  int v = cnt[i];
  int x = v;
  #pragma unroll
  for (int d = 1; d < 64; d <<= 1){
    int t = __shfl_up(x, d);
    if (lane >= d) x += t;
  }
  int excl = wpre[w] + x - v;
  offs[i] = excl; cursor[i] = excl;
  if (i == NTOT-1) offs[NTOT] = excl + v;
}

__global__ void k_scatter(const int* __restrict__ ei, int* __restrict__ cursor, int* __restrict__ csr){
  int e = blockIdx.x*256 + threadIdx.x;
  if (e < NE){
    int d = ei[NE + e], s = ei[e];
    int pos = atomicAdd(&cursor[d], 1);
    csr[pos] = s;
  }
}

// ---------------- per-node softmax + aggregation + scatter into x_seq ----------------
__global__ void __launch_bounds__(256) k_node(const float* __restrict__ hfeat, const float* __restrict__ asrc,
                      const float* __restrict__ adst, const int* __restrict__ offs,
                      const int* __restrict__ csr, const float* __restrict__ bias,
                      float* __restrict__ xseq){
  __shared__ float gsh[4][96];
  int wv = threadIdx.x >> 6, lane = threadIdx.x & 63;
  int n = blockIdx.x*4 + wv;
  int off = offs[n], deg = offs[n+1] - off;
  const float2* as2 = (const float2*)asrc;
  float2 adn = ((const float2*)adst)[n];
  float2 asn = as2[n];
  float es0 = __expf(lrelu(asn.x + adn.x));
  float es1 = __expf(lrelu(asn.y + adn.y));
  float s0 = 0.f, s1 = 0.f;
  for (int i = lane; i < deg; i += 64){
    int s = csr[off+i];
    float2 a = as2[s];
    s0 += __expf(lrelu(a.x + adn.x));
    s1 += __expf(lrelu(a.y + adn.y));
  }
  #pragma unroll
  for (int d = 1; d < 64; d <<= 1){
    s0 += __shfl_xor(s0, d);
    s1 += __shfl_xor(s1, d);
  }
  s0 += es0; s1 += es1;
  float inv0 = 1.f/(s0 + 1e-16f), inv1 = 1.f/(s1 + 1e-16f);
  int cl = (lane < 48) ? lane : lane - 48;
  float2 acc = make_float2(0.f, 0.f);
  {
    const float2* hr = (const float2*)(hfeat + (size_t)n*96);
    float2 r = hr[cl];
    float al = (lane < 24) ? es0*inv0 : es1*inv1;
    acc.x += r.x*al; acc.y += r.y*al;
  }
  int i = 0;
  for (; i + 4 <= deg; i += 4){
    int ss[4];
    #pragma unroll
    for (int j = 0; j < 4; ++j) ss[j] = csr[off+i+j];
    float2 aa[4];
    #pragma unroll
    for (int j = 0; j < 4; ++j) aa[j] = as2[ss[j]];
    #pragma unroll
    for (int j = 0; j < 4; ++j){
      const float2* hr = (const float2*)(hfeat + (size_t)ss[j]*96);
      float2 r = hr[cl];
      float w0 = __expf(lrelu(aa[j].x + adn.x));
      float w1 = __expf(lrelu(aa[j].y + adn.y));
      float al = (lane < 24) ? w0*inv0 : w1*inv1;
      acc.x += r.x*al; acc.y += r.y*al;
    }
  }
  for (; i < deg; ++i){
    int s = csr[off+i];
    float2 a = as2[s];
    const float2* hr = (const float2*)(hfeat + (size_t)s*96);
    float2 r = hr[cl];
    float w0 = __expf(lrelu(a.x + adn.x));
    float w1 = __expf(lrelu(a.y + adn.y));
    float al = (lane < 24) ? w0*inv0 : w1*inv1;
    acc.x += r.x*al; acc.y += r.y*al;
  }
  if (lane < 48){ gsh[wv][2*lane] = acc.x; gsh[wv][2*lane+1] = acc.y; }
  __syncthreads();
  if (lane < 48){
    float g = 0.5f*(gsh[wv][lane] + gsh[wv][48+lane]) + bias[lane];
    int b = n / 1000, node = n - b*1000;
    int t = lane >> 2, f = lane & 3;
    xseq[((size_t)(t*64 + b))*4000 + node*4 + f] = g;
  }
}

// ---------------- GEMM1: xw1_part = x_seq[768x4000] @ W_ih1^T[4000x1024], split-K=5 ----------------
__global__ void __launch_bounds__(256) k_gemm1(const float* __restrict__ A, const float* __restrict__ B,
                       float* __restrict__ part){
  __shared__ __align__(16) float As[32*72];
  __shared__ __align__(16) float Bs[32*72];
  int tid = threadIdx.x;
  int tx = tid & 15, ty = tid >> 4;
  int m0 = blockIdx.x*64, n0 = blockIdx.y*64;
  int k0 = blockIdx.z*800;
  float acc[4][4] = {};
  for (int kk = 0; kk < 800; kk += 32){
    #pragma unroll
    for (int l = 0; l < 2; ++l){
      int q = tid + l*256;
      int r = q >> 3, c4 = (q & 7)*4;
      float4 va = *(const float4*)(A + (size_t)(m0+r)*4000 + k0+kk+c4);
      As[(c4+0)*72 + r] = va.x; As[(c4+1)*72 + r] = va.y;
      As[(c4+2)*72 + r] = va.z; As[(c4+3)*72 + r] = va.w;
      float4 vb = *(const float4*)(B + (size_t)(n0+r)*4000 + k0+kk+c4);
      Bs[(c4+0)*72 + r] = vb.x; Bs[(c4+1)*72 + r] = vb.y;
      Bs[(c4+2)*72 + r] = vb.z; Bs[(c4+3)*72 + r] = vb.w;
    }
    __syncthreads();
    #pragma unroll
    for (int k = 0; k < 32; ++k){
      float4 a = *(const float4*)(&As[k*72 + ty*4]);
      float4 b = *(const float4*)(&Bs[k*72 + tx*4]);
      acc[0][0] += a.x*b.x; acc[0][1] += a.x*b.y; acc[0][2] += a.x*b.z; acc[0][3] += a.x*b.w;
      acc[1][0] += a.y*b.x; acc[1][1] += a.y*b.y; acc[1][2] += a.y*b.z; acc[1][3] += a.y*b.w;
      acc[2][0] += a.z*b.x; acc[2][1] += a.z*b.y; acc[2][2] += a.z*b.z; acc[2][3] += a.z*b.w;
      acc[3][0] += a.w*b.x; acc[3][1] += a.w*b.y; acc[3][2] += a.w*b.z; acc[3][3] += a.w*b.w;
    }
    __syncthreads();
  }
  #pragma unroll
  for (int i = 0; i < 4; ++i){
    float4 v; v.x = acc[i][0]; v.y = acc[i][1]; v.z = acc[i][2]; v.w = acc[i][3];
    *(float4*)(part + ((size_t)blockIdx.z*768 + m0 + ty*4 + i)*1024 + n0 + tx*4) = v;
  }
}

__global__ void k_reduce1(const float* __restrict__ part, const float* __restrict__ b1,
                          float* __restrict__ xw1){
  int i = blockIdx.x*256 + threadIdx.x;
  int j = i & 1023;
  float v = b1[j];
  #pragma unroll
  for (int s = 0; s < 5; ++s) v += part[(size_t)s*786432 + i];
  xw1[i] = v;
}

// ---------------- weight transposes (K-major for coalesced k_lstm dots) ----------------
__global__ void __launch_bounds__(256) k_tr(const float* __restrict__ Whh1, const float* __restrict__ Wih2,
                    const float* __restrict__ Whh2, const float* __restrict__ Wout,
                    float* __restrict__ dst){
  int i = blockIdx.x*256 + threadIdx.x;
  if (i < 262144){ int q = i>>10, r = i&1023; dst[i] = Whh1[r*256+q]; return; }
  i -= 262144;
  if (i < 131072){ int q = i>>9, r = i&511; dst[262144+i] = Wih2[r*256+q]; return; }
  i -= 131072;
  if (i < 65536){ int q = i>>9, r = i&511; dst[393216+i] = Whh2[(size_t)r*128+q]; return; }
  i -= 65536;
  if (i < 256000){ int q = i/2000, r = i - q*2000; dst[458752+i] = Wout[(size_t)r*128+q]; }
}

// ---------------- fused 2-layer LSTM + out-proj: ONE BLOCK PER BATCH ELEMENT ----------------
// Round-5 lesson: the LSTM recurrence is independent per batch element, so no
// cross-block sync is needed at all. Agent-scope fences on this chip are L2
// writeback/invalidates (per-XCD L2s non-coherent) -> the global-barrier design
// paid ~45us/phase in coherence traffic. Here: 64 blocks x 256 threads, h1/h2/p2
// in LDS, c1/c2 in registers, K-major weights -> all weight loads 64-lane coalesced.
__global__ void __launch_bounds__(256) k_lstm(
    const float* __restrict__ xw1, const float* __restrict__ Wt1,
    const float* __restrict__ Wt2i, const float* __restrict__ Wt2h,
    const float* __restrict__ b2, const float* __restrict__ Wt_o,
    const float* __restrict__ bout, float* __restrict__ out){
  __shared__ __align__(16) float h1s[256];
  __shared__ __align__(16) float h2s[128];
  __shared__ __align__(16) float p2s[512];
  int u = threadIdx.x;
  int b = blockIdx.x;
  float c1 = 0.f, c2 = 0.f;
  h1s[u] = 0.f;
  if (u < 128) h2s[u] = 0.f;
  __syncthreads();
  const float4* h14 = (const float4*)h1s;
  const float4* h24 = (const float4*)h2s;

  for (int t = 0; t < NSEQ; ++t){
    // ---- layer1 gates: thread u -> unit u; rows gi*256+u of Wt1 (K-major [256][1024]) ----
    float g1[4];
    {
      const float* xr = xw1 + ((size_t)t*64 + b)*1024 + u;
      #pragma unroll
      for (int gi = 0; gi < 4; ++gi) g1[gi] = xr[gi*256];
    }
    #pragma unroll 2
    for (int q4 = 0; q4 < 64; ++q4){
      float4 hv = h14[q4];
      float hq[4] = {hv.x, hv.y, hv.z, hv.w};
      const float* wb = Wt1 + (size_t)q4*4096 + u;
      #pragma unroll
      for (int j = 0; j < 4; ++j){
        const float* wr = wb + j*1024;
        float hj = hq[j];
        g1[0] += wr[0]  *hj;
        g1[1] += wr[256]*hj;
        g1[2] += wr[512]*hj;
        g1[3] += wr[768]*hj;
      }
    }
    float i1 = sigmoidf_(g1[0]);
    float f1 = sigmoidf_(g1[1]);
    float gg1 = tanhf(g1[2]);
    float o1 = sigmoidf_(g1[3]);
    c1 = f1*c1 + i1*gg1;
    float h1n = o1*tanhf(c1);
    __syncthreads();
    h1s[u] = h1n;
    __syncthreads();
    // ---- layer2 input proj (rows u, u+256 of Wt2i [256][512]) + hh2 partial (t<128) ----
    float d0 = b2[u], d1 = b2[u+256];
    #pragma unroll 2
    for (int q4 = 0; q4 < 64; ++q4){
      float4 hv = h14[q4];
      float hq[4] = {hv.x, hv.y, hv.z, hv.w};
      const float* wb = Wt2i + (size_t)q4*2048 + u;
      #pragma unroll
      for (int j = 0; j < 4; ++j){
        const float* wr = wb + j*512;
        float hj = hq[j];
        d0 += wr[0]  *hj;
        d1 += wr[256]*hj;
      }
    }
    float g2h[4] = {0.f, 0.f, 0.f, 0.f};
    if (u < 128){
      #pragma unroll 2
      for (int q4 = 0; q4 < 32; ++q4){
        float4 hv = h24[q4];
        float hq[4] = {hv.x, hv.y, hv.z, hv.w};
        const float* wb = Wt2h + (size_t)q4*2048 + u;
        #pragma unroll
        for (int j = 0; j < 4; ++j){
          const float* wr = wb + j*512;
          float hj = hq[j];
          g2h[0] += wr[0]  *hj;
          g2h[1] += wr[128]*hj;
          g2h[2] += wr[256]*hj;
          g2h[3] += wr[384]*hj;
        }
      }
    }
    p2s[u] = d0; p2s[u+256] = d1;
    __syncthreads();
    // ---- layer2 gates (threads < 128) ----
    if (u < 128){
      float g2[4];
      #pragma unroll
      for (int gi = 0; gi < 4; ++gi) g2[gi] = p2s[gi*128 + u] + g2h[gi];
      float i2 = sigmoidf_(g2[0]);
      float f2 = sigmoidf_(g2[1]);
      float gg2 = tanhf(g2[2]);
      float o2 = sigmoidf_(g2[3]);
      c2 = f2*c2 + i2*gg2;
      h2s[u] = o2*tanhf(c2);
    }
    // h2s write -> next read is layer2-hh (after 2 syncs) or out-proj (after sync) ✓
  }
  __syncthreads();
  // ---- output projection: out[b][j] = bout[j] + dot(Wt_o[:,j], h2) ----
  for (int j = u; j < 2000; j += 256){
    float acc = bout[j];
    #pragma unroll 2
    for (int q4 = 0; q4 < 32; ++q4){
      float4 hv = h24[q4];
      float hq[4] = {hv.x, hv.y, hv.z, hv.w};
      #pragma unroll
      for (int jj = 0; jj < 4; ++jj)
        acc += Wt_o[(size_t)(q4*4+jj)*2000 + j]*hq[jj];
    }
    out[(size_t)b*2000 + j] = acc;
  }
}

extern "C" void kernel_launch(void* const* d_in, const int* in_sizes, int n_in,
                              void* d_out, int out_size, void* d_ws, size_t ws_size,
                              hipStream_t stream){
  const float* x     = (const float*)d_in[0];
  const int*   ei    = (const int*)d_in[1];
  const float* Wg    = (const float*)d_in[2];
  const float* att_s = (const float*)d_in[3];
  const float* att_d = (const float*)d_in[4];
  const float* gb    = (const float*)d_in[5];
  const float* Wih1  = (const float*)d_in[6];
  const float* Whh1  = (const float*)d_in[7];
  const float* b1    = (const float*)d_in[8];
  const float* Wih2  = (const float*)d_in[9];
  const float* Whh2  = (const float*)d_in[10];
  const float* b2    = (const float*)d_in[11];
  const float* Wout  = (const float*)d_in[12];
  const float* bout  = (const float*)d_in[13];
  float* out = (float*)d_out;

  char* w = (char*)d_ws;
  float* xseq  = (float*)(w);                         // 12,288,000 B
  char*  hbase = w + 12288000;                        // hfeat region: 24,576,000 B
  float* hfeat = (float*)hbase;
  float* part  = (float*)(hbase);                     // 15,728,640 B (gemm1 out)
  float* xw1   = (float*)(hbase + 15728640);          //  3,145,728 B
  float* Wt1   = part;                                // 262144 f  (K-major Whh1)
  float* Wt2i  = part + 262144;                       // 131072 f  (K-major Wih2)
  float* Wt2h  = part + 393216;                       //  65536 f  (K-major Whh2)
  float* Wt_o  = part + 458752;                       // 256000 f  (K-major Wout)
  char*  p2 = w + 12288000 + 24576000;
  float* asrc   = (float*)(p2);
  float* adst   = (float*)(p2 + 512000);
  int*   cnt    = (int*)(p2 + 1024000);
  int*   offs   = (int*)(p2 + 1280000);
  int*   cursor = (int*)(p2 + 1536256);
  int*   csr    = (int*)(p2 + 1792256);
  int*   wsum   = csr;   // 4 KB alias: scan1/2/3 use it BEFORE k_scatter writes csr

  hipMemsetAsync(cnt, 0, NTOT*sizeof(int), stream);

  k_gat_h<<<250, 256, 0, stream>>>(x, Wg, att_s, att_d, hfeat, asrc, adst);
  k_count<<<4000, 256, 0, stream>>>(ei, cnt);
  k_scan1<<<250, 256, 0, stream>>>(cnt, wsum);
  k_scan2<<<1, 1024, 0, stream>>>(wsum);
  k_scan3<<<250, 256, 0, stream>>>(cnt, wsum, offs, cursor);
  k_scatter<<<4000, 256, 0, stream>>>(ei, cursor, csr);
  k_node<<<16000, 256, 0, stream>>>(hfeat, asrc, adst, offs, csr, gb, xseq);

  k_gemm1<<<dim3(12,16,5), 256, 0, stream>>>(xseq, Wih1, part);
  k_reduce1<<<3072, 256, 0, stream>>>(part, b1, xw1);
  k_tr<<<2792, 256, 0, stream>>>(Whh1, Wih2, Whh2, Wout, Wt1);

  k_lstm<<<NBATCH, 256, 0, stream>>>(xw1, Wt1, Wt2i, Wt2h, b2, Wt_o, bout, out);
}

// Round 7
// 526.315 us; speedup vs baseline: 1.9925x; 1.3366x over previous
//
#include <hip/hip_runtime.h>
#include <hip/hip_fp16.h>
#include <math.h>

#define NTOT   64000
#define NNODE  1000
#define NBATCH 64
#define NSEQ   12
#define NE     1024000

__device__ __forceinline__ float lrelu(float x){ return x > 0.f ? x : 0.2f*x; }
__device__ __forceinline__ float sigmoidf_(float x){ return 1.f/(1.f+__expf(-x)); }

// ---------------- GAT: h = x @ W_gat, per-node attention scalars ----------------
__global__ void __launch_bounds__(256) k_gat_h(const float* __restrict__ x, const float* __restrict__ Wg,
                       const float* __restrict__ att_s, const float* __restrict__ att_d,
                       float* __restrict__ hfeat, float* __restrict__ asrc, float* __restrict__ adst){
  __shared__ __align__(16) float Ws[48*96];
  __shared__ float as_s[96], ad_s[96];
  for (int i = threadIdx.x; i < 48*96; i += 256) Ws[i] = Wg[i];
  if (threadIdx.x < 96){ as_s[threadIdx.x] = att_s[threadIdx.x]; ad_s[threadIdx.x] = att_d[threadIdx.x]; }
  __syncthreads();
  int n = blockIdx.x * 256 + threadIdx.x;
  if (n >= NTOT) return;
  float xr[48];
  const float4* xv = (const float4*)(x + (size_t)n*48);
  #pragma unroll
  for (int q = 0; q < 12; ++q){ float4 v = xv[q]; xr[q*4]=v.x; xr[q*4+1]=v.y; xr[q*4+2]=v.z; xr[q*4+3]=v.w; }
  float a0=0.f,a1=0.f,d0=0.f,d1=0.f;
  float* hrow = hfeat + (size_t)n*96;
  for (int j = 0; j < 96; ++j){
    float acc = 0.f;
    #pragma unroll
    for (int k = 0; k < 48; ++k) acc += xr[k]*Ws[k*96+j];
    hrow[j] = acc;
    if (j < 48){ a0 += acc*as_s[j]; d0 += acc*ad_s[j]; }
    else       { a1 += acc*as_s[j]; d1 += acc*ad_s[j]; }
  }
  asrc[n*2]=a0; asrc[n*2+1]=a1; adst[n*2]=d0; adst[n*2+1]=d1;
}

// ---------------- CSR build ----------------
__global__ void k_count(const int* __restrict__ ei, int* __restrict__ cnt){
  int e = blockIdx.x*256 + threadIdx.x;
  if (e < NE) atomicAdd(&cnt[ei[NE + e]], 1);
}

__global__ void __launch_bounds__(256) k_scan1(const int* __restrict__ cnt, int* __restrict__ wsum){
  int w = (blockIdx.x*256 + threadIdx.x) >> 6;
  int lane = threadIdx.x & 63;
  int v = cnt[w*64 + lane];
  int t = v;
  #pragma unroll
  for (int d = 1; d < 64; d <<= 1) t += __shfl_xor(t, d);
  if (lane == 0) wsum[w] = t;
}

__global__ void __launch_bounds__(1024) k_scan2(int* __restrict__ wsum){
  __shared__ int tmp[1024];
  int k = threadIdx.x;
  int v = (k < 1000) ? wsum[k] : 0;
  tmp[k] = v; __syncthreads();
  for (int d = 1; d < 1024; d <<= 1){
    int t = (k >= d) ? tmp[k-d] : 0;
    __syncthreads();
    tmp[k] += t;
    __syncthreads();
  }
  if (k < 1000) wsum[k] = tmp[k] - v;
}

__global__ void __launch_bounds__(256) k_scan3(const int* __restrict__ cnt, const int* __restrict__ wpre,
                                               int* __restrict__ offs, int* __restrict__ cursor){
  int w = (blockIdx.x*256 + threadIdx.x) >> 6;
  int lane = threadIdx.x & 63;
  int i = w*64 + lane;
  int v = cnt[i];
  int x = v;
  #pragma unroll
  for (int d = 1; d < 64; d <<= 1){
    int t = __shfl_up(x, d);
    if (lane >= d) x += t;
  }
  int excl = wpre[w] + x - v;
  offs[i] = excl; cursor[i] = excl;
  if (i == NTOT-1) offs[NTOT] = excl + v;
}

__global__ void k_scatter(const int* __restrict__ ei, int* __restrict__ cursor, int* __restrict__ csr){
  int e = blockIdx.x*256 + threadIdx.x;
  if (e < NE){
    int d = ei[NE + e], s = ei[e];
    int pos = atomicAdd(&cursor[d], 1);
    csr[pos] = s;
  }
}

// ---------------- per-node softmax + aggregation + scatter into x_seq ----------------
__global__ void __launch_bounds__(256) k_node(const float* __restrict__ hfeat, const float* __restrict__ asrc,
                      const float* __restrict__ adst, const int* __restrict__ offs,
                      const int* __restrict__ csr, const float* __restrict__ bias,
                      float* __restrict__ xseq){
  __shared__ float gsh[4][96];
  int wv = threadIdx.x >> 6, lane = threadIdx.x & 63;
  int n = blockIdx.x*4 + wv;
  int off = offs[n], deg = offs[n+1] - off;
  const float2* as2 = (const float2*)asrc;
  float2 adn = ((const float2*)adst)[n];
  float2 asn = as2[n];
  float es0 = __expf(lrelu(asn.x + adn.x));
  float es1 = __expf(lrelu(asn.y + adn.y));
  float s0 = 0.f, s1 = 0.f;
  for (int i = lane; i < deg; i += 64){
    int s = csr[off+i];
    float2 a = as2[s];
    s0 += __expf(lrelu(a.x + adn.x));
    s1 += __expf(lrelu(a.y + adn.y));
  }
  #pragma unroll
  for (int d = 1; d < 64; d <<= 1){
    s0 += __shfl_xor(s0, d);
    s1 += __shfl_xor(s1, d);
  }
  s0 += es0; s1 += es1;
  float inv0 = 1.f/(s0 + 1e-16f), inv1 = 1.f/(s1 + 1e-16f);
  int cl = (lane < 48) ? lane : lane - 48;
  float2 acc = make_float2(0.f, 0.f);
  {
    const float2* hr = (const float2*)(hfeat + (size_t)n*96);
    float2 r = hr[cl];
    float al = (lane < 24) ? es0*inv0 : es1*inv1;
    acc.x += r.x*al; acc.y += r.y*al;
  }
  int i = 0;
  for (; i + 4 <= deg; i += 4){
    int ss[4];
    #pragma unroll
    for (int j = 0; j < 4; ++j) ss[j] = csr[off+i+j];
    float2 aa[4];
    #pragma unroll
    for (int j = 0; j < 4; ++j) aa[j] = as2[ss[j]];
    #pragma unroll
    for (int j = 0; j < 4; ++j){
      const float2* hr = (const float2*)(hfeat + (size_t)ss[j]*96);
      float2 r = hr[cl];
      float w0 = __expf(lrelu(aa[j].x + adn.x));
      float w1 = __expf(lrelu(aa[j].y + adn.y));
      float al = (lane < 24) ? w0*inv0 : w1*inv1;
      acc.x += r.x*al; acc.y += r.y*al;
    }
  }
  for (; i < deg; ++i){
    int s = csr[off+i];
    float2 a = as2[s];
    const float2* hr = (const float2*)(hfeat + (size_t)s*96);
    float2 r = hr[cl];
    float w0 = __expf(lrelu(a.x + adn.x));
    float w1 = __expf(lrelu(a.y + adn.y));
    float al = (lane < 24) ? w0*inv0 : w1*inv1;
    acc.x += r.x*al; acc.y += r.y*al;
  }
  if (lane < 48){ gsh[wv][2*lane] = acc.x; gsh[wv][2*lane+1] = acc.y; }
  __syncthreads();
  if (lane < 48){
    float g = 0.5f*(gsh[wv][lane] + gsh[wv][48+lane]) + bias[lane];
    int b = n / 1000, node = n - b*1000;
    int t = lane >> 2, f = lane & 3;
    xseq[((size_t)(t*64 + b))*4000 + node*4 + f] = g;
  }
}

// ---------------- GEMM1: xw1_part = x_seq[768x4000] @ W_ih1^T[4000x1024], split-K=5 ----------------
__global__ void __launch_bounds__(256) k_gemm1(const float* __restrict__ A, const float* __restrict__ B,
                       float* __restrict__ part){
  __shared__ __align__(16) float As[32*72];
  __shared__ __align__(16) float Bs[32*72];
  int tid = threadIdx.x;
  int tx = tid & 15, ty = tid >> 4;
  int m0 = blockIdx.x*64, n0 = blockIdx.y*64;
  int k0 = blockIdx.z*800;
  float acc[4][4] = {};
  for (int kk = 0; kk < 800; kk += 32){
    #pragma unroll
    for (int l = 0; l < 2; ++l){
      int q = tid + l*256;
      int r = q >> 3, c4 = (q & 7)*4;
      float4 va = *(const float4*)(A + (size_t)(m0+r)*4000 + k0+kk+c4);
      As[(c4+0)*72 + r] = va.x; As[(c4+1)*72 + r] = va.y;
      As[(c4+2)*72 + r] = va.z; As[(c4+3)*72 + r] = va.w;
      float4 vb = *(const float4*)(B + (size_t)(n0+r)*4000 + k0+kk+c4);
      Bs[(c4+0)*72 + r] = vb.x; Bs[(c4+1)*72 + r] = vb.y;
      Bs[(c4+2)*72 + r] = vb.z; Bs[(c4+3)*72 + r] = vb.w;
    }
    __syncthreads();
    #pragma unroll
    for (int k = 0; k < 32; ++k){
      float4 a = *(const float4*)(&As[k*72 + ty*4]);
      float4 b = *(const float4*)(&Bs[k*72 + tx*4]);
      acc[0][0] += a.x*b.x; acc[0][1] += a.x*b.y; acc[0][2] += a.x*b.z; acc[0][3] += a.x*b.w;
      acc[1][0] += a.y*b.x; acc[1][1] += a.y*b.y; acc[1][2] += a.y*b.z; acc[1][3] += a.y*b.w;
      acc[2][0] += a.z*b.x; acc[2][1] += a.z*b.y; acc[2][2] += a.z*b.z; acc[2][3] += a.z*b.w;
      acc[3][0] += a.w*b.x; acc[3][1] += a.w*b.y; acc[3][2] += a.w*b.z; acc[3][3] += a.w*b.w;
    }
    __syncthreads();
  }
  #pragma unroll
  for (int i = 0; i < 4; ++i){
    float4 v; v.x = acc[i][0]; v.y = acc[i][1]; v.z = acc[i][2]; v.w = acc[i][3];
    *(float4*)(part + ((size_t)blockIdx.z*768 + m0 + ty*4 + i)*1024 + n0 + tx*4) = v;
  }
}

__global__ void k_reduce1(const float* __restrict__ part, const float* __restrict__ b1,
                          float* __restrict__ xw1){
  int i = blockIdx.x*256 + threadIdx.x;
  int j = i & 1023;
  float v = b1[j];
  #pragma unroll
  for (int s = 0; s < 5; ++s) v += part[(size_t)s*786432 + i];
  xw1[i] = v;
}

// ---------------- weight transpose + fp16 convert (K-major) ----------------
// W1h [256][1024], W2ih [256][512], W2hh [128][512] (all K-major, fp16)
__global__ void __launch_bounds__(256) k_trh(const float* __restrict__ Whh1, const float* __restrict__ Wih2,
                    const float* __restrict__ Whh2, __half* __restrict__ dst){
  int i = blockIdx.x*256 + threadIdx.x;
  if (i < 262144){ int q = i>>10, r = i&1023; dst[i] = __float2half(Whh1[r*256+q]); return; }
  i -= 262144;
  if (i < 131072){ int q = i>>9, r = i&511; dst[262144+i] = __float2half(Wih2[r*256+q]); return; }
  i -= 131072;
  if (i < 65536){ int q = i>>9, r = i&511; dst[393216+i] = __float2half(Whh2[(size_t)r*128+q]); }
}

// ---------------- fused 2-layer LSTM: one block per batch, 1024 threads ----------------
// Round-6 lesson: 256 thr/block (1 wave/SIMD) + scalar dword weight loads was
// latency-bound (VALUBusy 5%, ~29 cyc/load). Fix: 16 waves/CU, 16B uint4 loads of
// fp16 weights (halves the per-CU weight stream), split-K partials reduced in LDS.
__global__ void __launch_bounds__(1024) k_lstm(
    const float* __restrict__ xw1, const __half* __restrict__ W1,
    const __half* __restrict__ W2i, const __half* __restrict__ W2h,
    const float* __restrict__ b2, float* __restrict__ h2o){
  __shared__ float h1s[256];
  __shared__ float h2s[128];
  __shared__ __align__(16) float pbuf[8192];
  int t = threadIdx.x;
  int b = blockIdx.x;
  // layer1 mapping: 8 K-chunks x 128 col-groups (8 cols each)
  int kk1 = t >> 7, c1c = (t & 127) * 8;
  // layer2 mapping: 16 K-chunks x 64 col-groups
  int kk2 = t >> 6, c2c = (t & 63) * 8;
  float cc1 = 0.f, cc2 = 0.f;
  float b2r[4] = {0.f,0.f,0.f,0.f};
  if (t < 128){
    #pragma unroll
    for (int gi = 0; gi < 4; ++gi) b2r[gi] = b2[gi*128 + t];
  }
  if (t < 256) h1s[t] = 0.f;
  if (t < 128) h2s[t] = 0.f;
  __syncthreads();

  for (int step = 0; step < NSEQ; ++step){
    // ---- layer1 partial dots: rows c1c..c1c+7, K-chunk kk1 ----
    {
      float acc[8] = {0,0,0,0,0,0,0,0};
      const __half* wp = W1 + (size_t)(kk1*32)*1024 + c1c;
      const float* hb = &h1s[kk1*32];
      #pragma unroll 4
      for (int q = 0; q < 32; ++q){
        uint4 wv = *(const uint4*)(wp + (size_t)q*1024);
        const __half2* hp = (const __half2*)&wv;
        float hq = hb[q];
        float2 f0 = __half22float2(hp[0]);
        float2 f1 = __half22float2(hp[1]);
        float2 f2 = __half22float2(hp[2]);
        float2 f3 = __half22float2(hp[3]);
        acc[0] += f0.x*hq; acc[1] += f0.y*hq;
        acc[2] += f1.x*hq; acc[3] += f1.y*hq;
        acc[4] += f2.x*hq; acc[5] += f2.y*hq;
        acc[6] += f3.x*hq; acc[7] += f3.y*hq;
      }
      float4 w0; w0.x=acc[0]; w0.y=acc[1]; w0.z=acc[2]; w0.w=acc[3];
      float4 w1; w1.x=acc[4]; w1.y=acc[5]; w1.z=acc[6]; w1.w=acc[7];
      *(float4*)&pbuf[kk1*1024 + c1c]     = w0;
      *(float4*)&pbuf[kk1*1024 + c1c + 4] = w1;
    }
    __syncthreads();
    // ---- layer1 reduce + gates (t<256 = unit t) ----
    if (t < 256){
      const float* xr = xw1 + ((size_t)step*64 + b)*1024 + t;
      float g[4];
      #pragma unroll
      for (int gi = 0; gi < 4; ++gi){
        float s = xr[gi*256];
        #pragma unroll
        for (int kk = 0; kk < 8; ++kk) s += pbuf[kk*1024 + gi*256 + t];
        g[gi] = s;
      }
      float i_ = sigmoidf_(g[0]);
      float f_ = sigmoidf_(g[1]);
      float gg = tanhf(g[2]);
      float o_ = sigmoidf_(g[3]);
      cc1 = f_*cc1 + i_*gg;
      h1s[t] = o_*tanhf(cc1);
    }
    __syncthreads();
    // ---- layer2 partial dots: ih over new h1 (K=256) + hh over old h2 (K=128) ----
    {
      float acc[8] = {0,0,0,0,0,0,0,0};
      const __half* wi = W2i + (size_t)(kk2*16)*512 + c2c;
      const float* hb1 = &h1s[kk2*16];
      #pragma unroll 4
      for (int q = 0; q < 16; ++q){
        uint4 wv = *(const uint4*)(wi + (size_t)q*512);
        const __half2* hp = (const __half2*)&wv;
        float hq = hb1[q];
        float2 f0 = __half22float2(hp[0]);
        float2 f1 = __half22float2(hp[1]);
        float2 f2 = __half22float2(hp[2]);
        float2 f3 = __half22float2(hp[3]);
        acc[0] += f0.x*hq; acc[1] += f0.y*hq;
        acc[2] += f1.x*hq; acc[3] += f1.y*hq;
        acc[4] += f2.x*hq; acc[5] += f2.y*hq;
        acc[6] += f3.x*hq; acc[7] += f3.y*hq;
      }
      const __half* wh = W2h + (size_t)(kk2*8)*512 + c2c;
      const float* hb2 = &h2s[kk2*8];
      #pragma unroll 4
      for (int q = 0; q < 8; ++q){
        uint4 wv = *(const uint4*)(wh + (size_t)q*512);
        const __half2* hp = (const __half2*)&wv;
        float hq = hb2[q];
        float2 f0 = __half22float2(hp[0]);
        float2 f1 = __half22float2(hp[1]);
        float2 f2 = __half22float2(hp[2]);
        float2 f3 = __half22float2(hp[3]);
        acc[0] += f0.x*hq; acc[1] += f0.y*hq;
        acc[2] += f1.x*hq; acc[3] += f1.y*hq;
        acc[4] += f2.x*hq; acc[5] += f2.y*hq;
        acc[6] += f3.x*hq; acc[7] += f3.y*hq;
      }
      float4 w0; w0.x=acc[0]; w0.y=acc[1]; w0.z=acc[2]; w0.w=acc[3];
      float4 w1; w1.x=acc[4]; w1.y=acc[5]; w1.z=acc[6]; w1.w=acc[7];
      *(float4*)&pbuf[kk2*512 + c2c]     = w0;
      *(float4*)&pbuf[kk2*512 + c2c + 4] = w1;
    }
    __syncthreads();
    // ---- layer2 reduce + gates (t<128 = unit t) ----
    if (t < 128){
      float g[4];
      #pragma unroll
      for (int gi = 0; gi < 4; ++gi){
        float s = b2r[gi];
        #pragma unroll
        for (int kk = 0; kk < 16; ++kk) s += pbuf[kk*512 + gi*128 + t];
        g[gi] = s;
      }
      float i_ = sigmoidf_(g[0]);
      float f_ = sigmoidf_(g[1]);
      float gg = tanhf(g[2]);
      float o_ = sigmoidf_(g[3]);
      cc2 = f_*cc2 + i_*gg;
      h2s[t] = o_*tanhf(cc2);
    }
    __syncthreads();
  }
  if (t < 128) h2o[(size_t)b*128 + t] = h2s[t];
}

// ---------------- output projection (wide grid, fp32 Wout direct) ----------------
__global__ void __launch_bounds__(256) k_out(const float* __restrict__ h2, const float* __restrict__ Wout,
                     const float* __restrict__ bout, float* __restrict__ out){
  __shared__ __align__(16) float hs[128];
  int b = blockIdx.y;
  if (threadIdx.x < 128) hs[threadIdx.x] = h2[(size_t)b*128 + threadIdx.x];
  __syncthreads();
  int j = blockIdx.x*256 + threadIdx.x;
  if (j >= 2000) return;
  const float4* w = (const float4*)(Wout + (size_t)j*128);
  const float4* hv = (const float4*)hs;
  float d = 0.f;
  for (int q = 0; q < 32; ++q){
    float4 a = hv[q], wv = w[q];
    d += a.x*wv.x + a.y*wv.y + a.z*wv.z + a.w*wv.w;
  }
  out[(size_t)b*2000 + j] = d + bout[j];
}

extern "C" void kernel_launch(void* const* d_in, const int* in_sizes, int n_in,
                              void* d_out, int out_size, void* d_ws, size_t ws_size,
                              hipStream_t stream){
  const float* x     = (const float*)d_in[0];
  const int*   ei    = (const int*)d_in[1];
  const float* Wg    = (const float*)d_in[2];
  const float* att_s = (const float*)d_in[3];
  const float* att_d = (const float*)d_in[4];
  const float* gb    = (const float*)d_in[5];
  const float* Wih1  = (const float*)d_in[6];
  const float* Whh1  = (const float*)d_in[7];
  const float* b1    = (const float*)d_in[8];
  const float* Wih2  = (const float*)d_in[9];
  const float* Whh2  = (const float*)d_in[10];
  const float* b2    = (const float*)d_in[11];
  const float* Wout  = (const float*)d_in[12];
  const float* bout  = (const float*)d_in[13];
  float* out = (float*)d_out;

  char* w = (char*)d_ws;
  float* xseq  = (float*)(w);                         // 12,288,000 B
  char*  hbase = w + 12288000;                        // hfeat region: 24,576,000 B
  float* hfeat = (float*)hbase;
  float* part  = (float*)(hbase);                     // 15,728,640 B (gemm1 out)
  float* xw1   = (float*)(hbase + 15728640);          //  3,145,728 B
  // fp16 K-major weights + h2 output live in part head (written after reduce1):
  __half* W1h  = (__half*)hbase;                      // 262144 h (524,288 B)
  __half* W2ih = W1h + 262144;                        // 131072 h
  __half* W2hh = W1h + 393216;                        //  65536 h (total 917,504 B)
  float* h2o   = (float*)(hbase + 1048576);           //  32,768 B
  char*  p2 = w + 12288000 + 24576000;
  float* asrc   = (float*)(p2);
  float* adst   = (float*)(p2 + 512000);
  int*   cnt    = (int*)(p2 + 1024000);
  int*   offs   = (int*)(p2 + 1280000);
  int*   cursor = (int*)(p2 + 1536256);
  int*   csr    = (int*)(p2 + 1792256);
  int*   wsum   = csr;   // 4 KB alias: scan1/2/3 use it BEFORE k_scatter writes csr

  hipMemsetAsync(cnt, 0, NTOT*sizeof(int), stream);

  k_gat_h<<<250, 256, 0, stream>>>(x, Wg, att_s, att_d, hfeat, asrc, adst);
  k_count<<<4000, 256, 0, stream>>>(ei, cnt);
  k_scan1<<<250, 256, 0, stream>>>(cnt, wsum);
  k_scan2<<<1, 1024, 0, stream>>>(wsum);
  k_scan3<<<250, 256, 0, stream>>>(cnt, wsum, offs, cursor);
  k_scatter<<<4000, 256, 0, stream>>>(ei, cursor, csr);
  k_node<<<16000, 256, 0, stream>>>(hfeat, asrc, adst, offs, csr, gb, xseq);

  k_gemm1<<<dim3(12,16,5), 256, 0, stream>>>(xseq, Wih1, part);
  k_reduce1<<<3072, 256, 0, stream>>>(part, b1, xw1);
  k_trh<<<1792, 256, 0, stream>>>(Whh1, Wih2, Whh2, W1h);

  k_lstm<<<NBATCH, 1024, 0, stream>>>(xw1, W1h, W2ih, W2hh, b2, h2o);
  k_out<<<dim3(8,64), 256, 0, stream>>>(h2o, Wout, bout, out);
}

// Round 8
// 467.089 us; speedup vs baseline: 2.2452x; 1.1268x over previous
//
#include <hip/hip_runtime.h>
#include <hip/hip_fp16.h>
#include <math.h>

#define NTOT   64000
#define NNODE  1000
#define NBATCH 64
#define NSEQ   12
#define NE     1024000

typedef _Float16 half8 __attribute__((ext_vector_type(8)));
typedef float f32x4 __attribute__((ext_vector_type(4)));

__device__ __forceinline__ float lrelu(float x){ return x > 0.f ? x : 0.2f*x; }
__device__ __forceinline__ float sigmoidf_(float x){ return 1.f/(1.f+__expf(-x)); }

// ---------------- GAT: h = x @ W_gat, per-node attention scalars ----------------
__global__ void __launch_bounds__(256) k_gat_h(const float* __restrict__ x, const float* __restrict__ Wg,
                       const float* __restrict__ att_s, const float* __restrict__ att_d,
                       float* __restrict__ hfeat, float* __restrict__ asrc, float* __restrict__ adst){
  __shared__ __align__(16) float Ws[48*96];
  __shared__ float as_s[96], ad_s[96];
  for (int i = threadIdx.x; i < 48*96; i += 256) Ws[i] = Wg[i];
  if (threadIdx.x < 96){ as_s[threadIdx.x] = att_s[threadIdx.x]; ad_s[threadIdx.x] = att_d[threadIdx.x]; }
  __syncthreads();
  int n = blockIdx.x * 256 + threadIdx.x;
  if (n >= NTOT) return;
  float xr[48];
  const float4* xv = (const float4*)(x + (size_t)n*48);
  #pragma unroll
  for (int q = 0; q < 12; ++q){ float4 v = xv[q]; xr[q*4]=v.x; xr[q*4+1]=v.y; xr[q*4+2]=v.z; xr[q*4+3]=v.w; }
  float a0=0.f,a1=0.f,d0=0.f,d1=0.f;
  float* hrow = hfeat + (size_t)n*96;
  for (int j = 0; j < 96; ++j){
    float acc = 0.f;
    #pragma unroll
    for (int k = 0; k < 48; ++k) acc += xr[k]*Ws[k*96+j];
    hrow[j] = acc;
    if (j < 48){ a0 += acc*as_s[j]; d0 += acc*ad_s[j]; }
    else       { a1 += acc*as_s[j]; d1 += acc*ad_s[j]; }
  }
  asrc[n*2]=a0; asrc[n*2+1]=a1; adst[n*2]=d0; adst[n*2+1]=d1;
}

// ---------------- CSR build ----------------
__global__ void k_count(const int* __restrict__ ei, int* __restrict__ cnt){
  int e = blockIdx.x*256 + threadIdx.x;
  if (e < NE) atomicAdd(&cnt[ei[NE + e]], 1);
}

__global__ void __launch_bounds__(256) k_scan1(const int* __restrict__ cnt, int* __restrict__ wsum){
  int w = (blockIdx.x*256 + threadIdx.x) >> 6;
  int lane = threadIdx.x & 63;
  int v = cnt[w*64 + lane];
  int t = v;
  #pragma unroll
  for (int d = 1; d < 64; d <<= 1) t += __shfl_xor(t, d);
  if (lane == 0) wsum[w] = t;
}

__global__ void __launch_bounds__(1024) k_scan2(int* __restrict__ wsum){
  __shared__ int tmp[1024];
  int k = threadIdx.x;
  int v = (k < 1000) ? wsum[k] : 0;
  tmp[k] = v; __syncthreads();
  for (int d = 1; d < 1024; d <<= 1){
    int t = (k >= d) ? tmp[k-d] : 0;
    __syncthreads();
    tmp[k] += t;
    __syncthreads();
  }
  if (k < 1000) wsum[k] = tmp[k] - v;
}

__global__ void __launch_bounds__(256) k_scan3(const int* __restrict__ cnt, const int* __restrict__ wpre,
                                               int* __restrict__ offs, int* __restrict__ cursor){
  int w = (blockIdx.x*256 + threadIdx.x) >> 6;
  int lane = threadIdx.x & 63;
  int i = w*64 + lane;
  int v = cnt[i];
  int x = v;
  #pragma unroll
  for (int d = 1; d < 64; d <<= 1){
    int t = __shfl_up(x, d);
    if (lane >= d) x += t;
  }
  int excl = wpre[w] + x - v;
  offs[i] = excl; cursor[i] = excl;
  if (i == NTOT-1) offs[NTOT] = excl + v;
}

__global__ void k_scatter(const int* __restrict__ ei, int* __restrict__ cursor, int* __restrict__ csr){
  int e = blockIdx.x*256 + threadIdx.x;
  if (e < NE){
    int d = ei[NE + e], s = ei[e];
    int pos = atomicAdd(&cursor[d], 1);
    csr[pos] = s;
  }
}

// ---------------- per-node softmax + aggregation + scatter into x_seq (fp16) ----------------
__global__ void __launch_bounds__(256) k_node(const float* __restrict__ hfeat, const float* __restrict__ asrc,
                      const float* __restrict__ adst, const int* __restrict__ offs,
                      const int* __restrict__ csr, const float* __restrict__ bias,
                      _Float16* __restrict__ xseqh){
  __shared__ float gsh[4][96];
  int wv = threadIdx.x >> 6, lane = threadIdx.x & 63;
  int n = blockIdx.x*4 + wv;
  int off = offs[n], deg = offs[n+1] - off;
  const float2* as2 = (const float2*)asrc;
  float2 adn = ((const float2*)adst)[n];
  float2 asn = as2[n];
  float es0 = __expf(lrelu(asn.x + adn.x));
  float es1 = __expf(lrelu(asn.y + adn.y));
  float s0 = 0.f, s1 = 0.f;
  for (int i = lane; i < deg; i += 64){
    int s = csr[off+i];
    float2 a = as2[s];
    s0 += __expf(lrelu(a.x + adn.x));
    s1 += __expf(lrelu(a.y + adn.y));
  }
  #pragma unroll
  for (int d = 1; d < 64; d <<= 1){
    s0 += __shfl_xor(s0, d);
    s1 += __shfl_xor(s1, d);
  }
  s0 += es0; s1 += es1;
  float inv0 = 1.f/(s0 + 1e-16f), inv1 = 1.f/(s1 + 1e-16f);
  int cl = (lane < 48) ? lane : lane - 48;
  float2 acc = make_float2(0.f, 0.f);
  {
    const float2* hr = (const float2*)(hfeat + (size_t)n*96);
    float2 r = hr[cl];
    float al = (lane < 24) ? es0*inv0 : es1*inv1;
    acc.x += r.x*al; acc.y += r.y*al;
  }
  int i = 0;
  for (; i + 4 <= deg; i += 4){
    int ss[4];
    #pragma unroll
    for (int j = 0; j < 4; ++j) ss[j] = csr[off+i+j];
    float2 aa[4];
    #pragma unroll
    for (int j = 0; j < 4; ++j) aa[j] = as2[ss[j]];
    #pragma unroll
    for (int j = 0; j < 4; ++j){
      const float2* hr = (const float2*)(hfeat + (size_t)ss[j]*96);
      float2 r = hr[cl];
      float w0 = __expf(lrelu(aa[j].x + adn.x));
      float w1 = __expf(lrelu(aa[j].y + adn.y));
      float al = (lane < 24) ? w0*inv0 : w1*inv1;
      acc.x += r.x*al; acc.y += r.y*al;
    }
  }
  for (; i < deg; ++i){
    int s = csr[off+i];
    float2 a = as2[s];
    const float2* hr = (const float2*)(hfeat + (size_t)s*96);
    float2 r = hr[cl];
    float w0 = __expf(lrelu(a.x + adn.x));
    float w1 = __expf(lrelu(a.y + adn.y));
    float al = (lane < 24) ? w0*inv0 : w1*inv1;
    acc.x += r.x*al; acc.y += r.y*al;
  }
  if (lane < 48){ gsh[wv][2*lane] = acc.x; gsh[wv][2*lane+1] = acc.y; }
  __syncthreads();
  if (lane < 48){
    float g = 0.5f*(gsh[wv][lane] + gsh[wv][48+lane]) + bias[lane];
    int b = n / 1000, node = n - b*1000;
    int t = lane >> 2, f = lane & 3;
    xseqh[((size_t)(t*64 + b))*4000 + node*4 + f] = (_Float16)g;
  }
}

// ---------------- Wih1 fp32 -> fp16 (same [1024][4000] layout) ----------------
__global__ void __launch_bounds__(256) k_cvt(const float* __restrict__ W, _Float16* __restrict__ dst){
  int i = blockIdx.x*256 + threadIdx.x;   // 1,024,000 threads x 4 elems
  float4 v = *(const float4*)(W + (size_t)i*4);
  union { _Float16 h[4]; uint2 u; } o;
  o.h[0] = (_Float16)v.x; o.h[1] = (_Float16)v.y;
  o.h[2] = (_Float16)v.z; o.h[3] = (_Float16)v.w;
  *(uint2*)(dst + (size_t)i*4) = o.u;
}

// ---------------- GEMM1 on matrix cores: xw1 = xseq_h @ Wih1_h^T + b1 ----------------
// C[768][1024], K=4000. mfma_f32_16x16x32_f16, 64x64 tile, 4 waves (16x64 strip each),
// BK=32, LDS stride 40 halves, register-prefetch of next global tile.
__global__ void __launch_bounds__(256) k_gemm1h(const _Float16* __restrict__ A,
                        const _Float16* __restrict__ B, const float* __restrict__ b1,
                        float* __restrict__ xw1){
  __shared__ _Float16 As[64*40];
  __shared__ _Float16 Bs[64*40];
  int tid = threadIdx.x;
  int w = tid >> 6, l = tid & 63;
  int m0 = blockIdx.x*64, n0 = blockIdx.y*64;
  int fr = l & 15, fk = (l >> 4)*8;
  f32x4 acc0 = {0.f,0.f,0.f,0.f}, acc1 = acc0, acc2 = acc0, acc3 = acc0;
  int ra = tid >> 2, ca = (tid & 3)*8;
  const _Float16* Ap = A + (size_t)(m0+ra)*4000 + ca;
  const _Float16* Bp = B + (size_t)(n0+ra)*4000 + ca;
  _Float16* Asw = &As[ra*40 + ca];
  _Float16* Bsw = &Bs[ra*40 + ca];
  half8 pa = *(const half8*)Ap;
  half8 pb = *(const half8*)Bp;
  for (int k0 = 0; k0 < 4000; k0 += 32){
    *(half8*)Asw = pa;
    *(half8*)Bsw = pb;
    __syncthreads();
    if (k0 + 32 < 4000){
      pa = *(const half8*)(Ap + k0 + 32);
      pb = *(const half8*)(Bp + k0 + 32);
    }
    half8 af  = *(const half8*)&As[(w*16 + fr)*40 + fk];
    half8 bf0 = *(const half8*)&Bs[( 0 + fr)*40 + fk];
    half8 bf1 = *(const half8*)&Bs[(16 + fr)*40 + fk];
    half8 bf2 = *(const half8*)&Bs[(32 + fr)*40 + fk];
    half8 bf3 = *(const half8*)&Bs[(48 + fr)*40 + fk];
    acc0 = __builtin_amdgcn_mfma_f32_16x16x32_f16(af, bf0, acc0, 0, 0, 0);
    acc1 = __builtin_amdgcn_mfma_f32_16x16x32_f16(af, bf1, acc1, 0, 0, 0);
    acc2 = __builtin_amdgcn_mfma_f32_16x16x32_f16(af, bf2, acc2, 0, 0, 0);
    acc3 = __builtin_amdgcn_mfma_f32_16x16x32_f16(af, bf3, acc3, 0, 0, 0);
    __syncthreads();
  }
  // D layout: row m = (l>>4)*4 + reg, col n = l&15  [verified m89/m91 mapping]
  int mrow = m0 + w*16 + (l >> 4)*4;
  int ncol = n0 + (l & 15);
  float bb0 = b1[ncol], bb1 = b1[ncol+16], bb2 = b1[ncol+32], bb3 = b1[ncol+48];
  #pragma unroll
  for (int r = 0; r < 4; ++r){
    float* cp = xw1 + (size_t)(mrow + r)*1024 + ncol;
    cp[0]  = acc0[r] + bb0;
    cp[16] = acc1[r] + bb1;
    cp[32] = acc2[r] + bb2;
    cp[48] = acc3[r] + bb3;
  }
}

// ---------------- weight transpose + fp16 convert (K-major) for LSTM ----------------
__global__ void __launch_bounds__(256) k_trh(const float* __restrict__ Whh1, const float* __restrict__ Wih2,
                    const float* __restrict__ Whh2, __half* __restrict__ dst){
  int i = blockIdx.x*256 + threadIdx.x;
  if (i < 262144){ int q = i>>10, r = i&1023; dst[i] = __float2half(Whh1[r*256+q]); return; }
  i -= 262144;
  if (i < 131072){ int q = i>>9, r = i&511; dst[262144+i] = __float2half(Wih2[r*256+q]); return; }
  i -= 131072;
  if (i < 65536){ int q = i>>9, r = i&511; dst[393216+i] = __float2half(Whh2[(size_t)r*128+q]); }
}

// ---------------- fused 2-layer LSTM: one block per batch, 1024 threads ----------------
__global__ void __launch_bounds__(1024) k_lstm(
    const float* __restrict__ xw1, const __half* __restrict__ W1,
    const __half* __restrict__ W2i, const __half* __restrict__ W2h,
    const float* __restrict__ b2, float* __restrict__ h2o){
  __shared__ float h1s[256];
  __shared__ float h2s[128];
  __shared__ __align__(16) float pbuf[8192];
  int t = threadIdx.x;
  int b = blockIdx.x;
  int kk1 = t >> 7, c1c = (t & 127) * 8;
  int kk2 = t >> 6, c2c = (t & 63) * 8;
  float cc1 = 0.f, cc2 = 0.f;
  float b2r[4] = {0.f,0.f,0.f,0.f};
  if (t < 128){
    #pragma unroll
    for (int gi = 0; gi < 4; ++gi) b2r[gi] = b2[gi*128 + t];
  }
  if (t < 256) h1s[t] = 0.f;
  if (t < 128) h2s[t] = 0.f;
  __syncthreads();

  for (int step = 0; step < NSEQ; ++step){
    {
      float acc[8] = {0,0,0,0,0,0,0,0};
      const __half* wp = W1 + (size_t)(kk1*32)*1024 + c1c;
      const float* hb = &h1s[kk1*32];
      #pragma unroll 4
      for (int q = 0; q < 32; ++q){
        uint4 wv = *(const uint4*)(wp + (size_t)q*1024);
        const __half2* hp = (const __half2*)&wv;
        float hq = hb[q];
        float2 f0 = __half22float2(hp[0]);
        float2 f1 = __half22float2(hp[1]);
        float2 f2 = __half22float2(hp[2]);
        float2 f3 = __half22float2(hp[3]);
        acc[0] += f0.x*hq; acc[1] += f0.y*hq;
        acc[2] += f1.x*hq; acc[3] += f1.y*hq;
        acc[4] += f2.x*hq; acc[5] += f2.y*hq;
        acc[6] += f3.x*hq; acc[7] += f3.y*hq;
      }
      float4 w0; w0.x=acc[0]; w0.y=acc[1]; w0.z=acc[2]; w0.w=acc[3];
      float4 w1; w1.x=acc[4]; w1.y=acc[5]; w1.z=acc[6]; w1.w=acc[7];
      *(float4*)&pbuf[kk1*1024 + c1c]     = w0;
      *(float4*)&pbuf[kk1*1024 + c1c + 4] = w1;
    }
    __syncthreads();
    if (t < 256){
      const float* xr = xw1 + ((size_t)step*64 + b)*1024 + t;
      float g[4];
      #pragma unroll
      for (int gi = 0; gi < 4; ++gi){
        float s = xr[gi*256];
        #pragma unroll
        for (int kk = 0; kk < 8; ++kk) s += pbuf[kk*1024 + gi*256 + t];
        g[gi] = s;
      }
      float i_ = sigmoidf_(g[0]);
      float f_ = sigmoidf_(g[1]);
      float gg = tanhf(g[2]);
      float o_ = sigmoidf_(g[3]);
      cc1 = f_*cc1 + i_*gg;
      h1s[t] = o_*tanhf(cc1);
    }
    __syncthreads();
    {
      float acc[8] = {0,0,0,0,0,0,0,0};
      const __half* wi = W2i + (size_t)(kk2*16)*512 + c2c;
      const float* hb1 = &h1s[kk2*16];
      #pragma unroll 4
      for (int q = 0; q < 16; ++q){
        uint4 wv = *(const uint4*)(wi + (size_t)q*512);
        const __half2* hp = (const __half2*)&wv;
        float hq = hb1[q];
        float2 f0 = __half22float2(hp[0]);
        float2 f1 = __half22float2(hp[1]);
        float2 f2 = __half22float2(hp[2]);
        float2 f3 = __half22float2(hp[3]);
        acc[0] += f0.x*hq; acc[1] += f0.y*hq;
        acc[2] += f1.x*hq; acc[3] += f1.y*hq;
        acc[4] += f2.x*hq; acc[5] += f2.y*hq;
        acc[6] += f3.x*hq; acc[7] += f3.y*hq;
      }
      const __half* wh = W2h + (size_t)(kk2*8)*512 + c2c;
      const float* hb2 = &h2s[kk2*8];
      #pragma unroll 4
      for (int q = 0; q < 8; ++q){
        uint4 wv = *(const uint4*)(wh + (size_t)q*512);
        const __half2* hp = (const __half2*)&wv;
        float hq = hb2[q];
        float2 f0 = __half22float2(hp[0]);
        float2 f1 = __half22float2(hp[1]);
        float2 f2 = __half22float2(hp[2]);
        float2 f3 = __half22float2(hp[3]);
        acc[0] += f0.x*hq; acc[1] += f0.y*hq;
        acc[2] += f1.x*hq; acc[3] += f1.y*hq;
        acc[4] += f2.x*hq; acc[5] += f2.y*hq;
        acc[6] += f3.x*hq; acc[7] += f3.y*hq;
      }
      float4 w0; w0.x=acc[0]; w0.y=acc[1]; w0.z=acc[2]; w0.w=acc[3];
      float4 w1; w1.x=acc[4]; w1.y=acc[5]; w1.z=acc[6]; w1.w=acc[7];
      *(float4*)&pbuf[kk2*512 + c2c]     = w0;
      *(float4*)&pbuf[kk2*512 + c2c + 4] = w1;
    }
    __syncthreads();
    if (t < 128){
      float g[4];
      #pragma unroll
      for (int gi = 0; gi < 4; ++gi){
        float s = b2r[gi];
        #pragma unroll
        for (int kk = 0; kk < 16; ++kk) s += pbuf[kk*512 + gi*128 + t];
        g[gi] = s;
      }
      float i_ = sigmoidf_(g[0]);
      float f_ = sigmoidf_(g[1]);
      float gg = tanhf(g[2]);
      float o_ = sigmoidf_(g[3]);
      cc2 = f_*cc2 + i_*gg;
      h2s[t] = o_*tanhf(cc2);
    }
    __syncthreads();
  }
  if (t < 128) h2o[(size_t)b*128 + t] = h2s[t];
}

// ---------------- output projection ----------------
__global__ void __launch_bounds__(256) k_out(const float* __restrict__ h2, const float* __restrict__ Wout,
                     const float* __restrict__ bout, float* __restrict__ out){
  __shared__ __align__(16) float hs[128];
  int b = blockIdx.y;
  if (threadIdx.x < 128) hs[threadIdx.x] = h2[(size_t)b*128 + threadIdx.x];
  __syncthreads();
  int j = blockIdx.x*256 + threadIdx.x;
  if (j >= 2000) return;
  const float4* w = (const float4*)(Wout + (size_t)j*128);
  const float4* hv = (const float4*)hs;
  float d = 0.f;
  for (int q = 0; q < 32; ++q){
    float4 a = hv[q], wv = w[q];
    d += a.x*wv.x + a.y*wv.y + a.z*wv.z + a.w*wv.w;
  }
  out[(size_t)b*2000 + j] = d + bout[j];
}

extern "C" void kernel_launch(void* const* d_in, const int* in_sizes, int n_in,
                              void* d_out, int out_size, void* d_ws, size_t ws_size,
                              hipStream_t stream){
  const float* x     = (const float*)d_in[0];
  const int*   ei    = (const int*)d_in[1];
  const float* Wg    = (const float*)d_in[2];
  const float* att_s = (const float*)d_in[3];
  const float* att_d = (const float*)d_in[4];
  const float* gb    = (const float*)d_in[5];
  const float* Wih1  = (const float*)d_in[6];
  const float* Whh1  = (const float*)d_in[7];
  const float* b1    = (const float*)d_in[8];
  const float* Wih2  = (const float*)d_in[9];
  const float* Whh2  = (const float*)d_in[10];
  const float* b2    = (const float*)d_in[11];
  const float* Wout  = (const float*)d_in[12];
  const float* bout  = (const float*)d_in[13];
  float* out = (float*)d_out;

  char* w = (char*)d_ws;
  _Float16* xseqh = (_Float16*)w;                     // 6,144,000 B (region 12.29 MB)
  char*  hbase = w + 12288000;                        // hfeat region: 24,576,000 B
  float* hfeat = (float*)hbase;                       // alive until k_node completes
  // aliases inside hfeat region, all written AFTER k_node:
  _Float16* Bh  = (_Float16*)hbase;                   // 8,192,000 B (fp16 Wih1)
  float* xw1    = (float*)(hbase + 8192000);          // 3,145,728 B
  __half* W1h   = (__half*)(hbase + 11337728);        //   917,504 B (K-major fp16 LSTM wts)
  float* h2o    = (float*)(hbase + 12255232);         //    32,768 B
  char*  p2 = w + 12288000 + 24576000;
  float* asrc   = (float*)(p2);
  float* adst   = (float*)(p2 + 512000);
  int*   cnt    = (int*)(p2 + 1024000);
  int*   offs   = (int*)(p2 + 1280000);
  int*   cursor = (int*)(p2 + 1536256);
  int*   csr    = (int*)(p2 + 1792256);
  int*   wsum   = csr;   // 4 KB alias: scan1/2/3 use it BEFORE k_scatter writes csr

  hipMemsetAsync(cnt, 0, NTOT*sizeof(int), stream);

  k_gat_h<<<250, 256, 0, stream>>>(x, Wg, att_s, att_d, hfeat, asrc, adst);
  k_count<<<4000, 256, 0, stream>>>(ei, cnt);
  k_scan1<<<250, 256, 0, stream>>>(cnt, wsum);
  k_scan2<<<1, 1024, 0, stream>>>(wsum);
  k_scan3<<<250, 256, 0, stream>>>(cnt, wsum, offs, cursor);
  k_scatter<<<4000, 256, 0, stream>>>(ei, cursor, csr);
  k_node<<<16000, 256, 0, stream>>>(hfeat, asrc, adst, offs, csr, gb, xseqh);

  // hfeat dead from here; its region hosts Bh / xw1 / W1h / h2o
  k_cvt<<<4000, 256, 0, stream>>>(Wih1, Bh);
  k_trh<<<1792, 256, 0, stream>>>(Whh1, Wih2, Whh2, W1h);
  k_gemm1h<<<dim3(12,16), 256, 0, stream>>>(xseqh, Bh, b1, xw1);

  k_lstm<<<NBATCH, 1024, 0, stream>>>(xw1, W1h, W1h + 262144, W1h + 393216, b2, h2o);
  k_out<<<dim3(8,64), 256, 0, stream>>>(h2o, Wout, bout, out);
}